// Round 13
// baseline (628.788 us; speedup 1.0000x reference)
//
#include <hip/hip_runtime.h>

// Exponential smoothing: s[-1]=v0; s[j] = w*s[j-1] + (1-w)*x[j]; out[j]=s[j]
// w = sigmoid(smoothing_weight[h]).
// Round-13: WAVE-AUTONOMOUS single-pass scan. Each 64-lane wave owns
// (batch b, chunk c of TS=8 steps, channel-half h); lane = one float4
// channel. x[8] float4 = 32 data VGPRs per lane (round-10's proven
// spill-free shape). No __syncthreads in the hot path, no LDS staging:
//   load+fold A -> publish A -> hierarchical carry walk (<=21 polls) ->
//   publish S1/S2 if producer -> scan -> NT store.
// 3-level hierarchy (NC=512 = 8x8x8): A (chunk, w^8), S1 (8 chunks, w^64),
// S2 (64 chunks, w^512). S1 producer reuses its remainder fold R; S2
// producer keeps a zero-seed Z during the m-walk => publishers never wait
// on anything a dependent needs first.
// Inter-wave comm: relaxed agent atomics + 0xFFFFFFFF sentinel only (no
// fences). Fixed-order folds => bit-deterministic. Per-block ticket keeps
// dependency-order = dispatch-order => progress under any residency.

namespace {

constexpr int Bt   = 16;            // batch
constexpr int Tt   = 4096;          // time
constexpr int HD4  = 128;           // float4 channels per (b,t)
constexpr int TSv  = 8;             // time-steps per wave (chunk length)
constexpr int NC   = Tt / TSv;      // 512 chunks per batch
constexpr int WPB  = 8;             // waves per block (512 threads)
constexpr int NWAVE = NC * Bt * 2;  // 16384 waves (2 channel-halves)
constexpr int NBLK  = NWAVE / WPB;  // 2048 blocks
constexpr unsigned SENT = 0xFFFFFFFFu;

// float4 slot counts for the three aggregate levels
constexpr size_t A_F4  = (size_t)NC * Bt * 2 * 64;        // 1,048,576 (16 MiB)
constexpr size_t S1_F4 = (size_t)(NC / 8) * Bt * 2 * 64;  // 131,072   (2 MiB)
constexpr size_t S2_F4 = (size_t)(NC / 64) * Bt * 2 * 64; // 16,384    (256 KiB)

typedef float fvec4 __attribute__((ext_vector_type(4)));

__device__ __forceinline__ float sigmoidf_(float x) {
    return 1.0f / (1.0f + expf(-x));
}

__device__ __forceinline__ unsigned ld_relaxed(const unsigned* p) {
    return __hip_atomic_load(p, __ATOMIC_RELAXED, __HIP_MEMORY_SCOPE_AGENT);
}

__device__ __forceinline__ float4 poll4(const float* pf) {
    const unsigned* p = (const unsigned*)pf;
    unsigned u0, u1, u2, u3;
    for (;;) {
        u0 = ld_relaxed(p + 0); u1 = ld_relaxed(p + 1);
        u2 = ld_relaxed(p + 2); u3 = ld_relaxed(p + 3);
        if (u0 != SENT && u1 != SENT && u2 != SENT && u3 != SENT) break;
        __builtin_amdgcn_s_sleep(2);
    }
    return make_float4(__uint_as_float(u0), __uint_as_float(u1),
                       __uint_as_float(u2), __uint_as_float(u3));
}

__device__ __forceinline__ void store1(float* p, float v) {
    __hip_atomic_store(p, v, __ATOMIC_RELAXED, __HIP_MEMORY_SCOPE_AGENT);
}

__device__ __forceinline__ void store4(float* p, const float4& v) {
    store1(p + 0, v.x); store1(p + 1, v.y);
    store1(p + 2, v.z); store1(p + 3, v.w);
}

__global__ __launch_bounds__(512) void ema_wave(
    const float4* __restrict__ values4, const float* __restrict__ sw,
    const float4* __restrict__ v04, float4* __restrict__ out4,
    float* __restrict__ aggA, float* __restrict__ aggS1,
    float* __restrict__ aggS2, int* __restrict__ ticket) {

    __shared__ int s_t;
    if (threadIdx.x == 0) s_t = atomicAdd(ticket, 1);
    __syncthreads();   // only barrier: ticket broadcast at kernel start
    const int lane = threadIdx.x & 63;
    const int wv   = threadIdx.x >> 6;
    const int vid  = s_t * WPB + wv;     // c-major => deps have lower vid
    const int c = vid >> 5;              // chunk 0..511
    const int b = (vid >> 1) & (Bt - 1);
    const int h = vid & 1;               // channel half
    const int ch4 = h * 64 + lane;       // float4 channel 0..127

    const float w   = sigmoidf_(sw[ch4 >> 4]);
    const float omw = 1.0f - w;
    float W1 = w * w;   W1 *= W1; W1 *= W1;     // w^8
    float W2 = W1 * W1; W2 *= W2; W2 *= W2;     // w^64
    float W3 = W2 * W2; W3 *= W3; W3 *= W3;     // w^512

    // Load my 8 steps (coalesced 1 KiB per load across the wave); fold A.
    const size_t base = ((size_t)b * Tt + (size_t)c * TSv) * HD4 + ch4;
    const float4* p = values4 + base;
    float4 x[TSv];
    float4 A = make_float4(0.f, 0.f, 0.f, 0.f);
    #pragma unroll
    for (int u = 0; u < TSv; ++u) {
        x[u] = p[(size_t)u * HD4];
        A.x = fmaf(w, A.x, omw * x[u].x);
        A.y = fmaf(w, A.y, omw * x[u].y);
        A.z = fmaf(w, A.z, omw * x[u].z);
        A.w = fmaf(w, A.w, omw * x[u].w);
    }
    #pragma unroll
    for (int u = 0; u < TSv; ++u)
        asm volatile("" : "+v"(x[u].x), "+v"(x[u].y), "+v"(x[u].z), "+v"(x[u].w));

    // Publish chunk aggregate immediately (wait-free).
    const size_t slot = (((size_t)c * Bt + b) * 2 + h) * 64 + lane;
    store4(aggA + slot * 4, A);

    // Hierarchical carry walk: c = 64q + 8m + r.
    const int q = c >> 6, m = (c >> 3) & 7, r = c & 7;
    float4 P = v04[ch4];
    float4 Z = make_float4(0.f, 0.f, 0.f, 0.f);   // zero-seed S1 fold (for S2)
    float4 R = make_float4(0.f, 0.f, 0.f, 0.f);   // zero-seed A fold (for S1)
    #pragma unroll
    for (int j = 0; j < 7; ++j) {
        if (j < q) {
            float4 v = poll4(aggS2 + ((((size_t)j * Bt + b) * 2 + h) * 64 + lane) * 4);
            P.x = fmaf(W3, P.x, v.x); P.y = fmaf(W3, P.y, v.y);
            P.z = fmaf(W3, P.z, v.z); P.w = fmaf(W3, P.w, v.w);
        }
    }
    #pragma unroll
    for (int j = 0; j < 7; ++j) {
        if (j < m) {
            float4 v = poll4(aggS1 + ((((size_t)(q * 8 + j) * Bt + b) * 2 + h) * 64 + lane) * 4);
            P.x = fmaf(W2, P.x, v.x); P.y = fmaf(W2, P.y, v.y);
            P.z = fmaf(W2, P.z, v.z); P.w = fmaf(W2, P.w, v.w);
            Z.x = fmaf(W2, Z.x, v.x); Z.y = fmaf(W2, Z.y, v.y);
            Z.z = fmaf(W2, Z.z, v.z); Z.w = fmaf(W2, Z.w, v.w);
        }
    }
    #pragma unroll
    for (int j = 0; j < 7; ++j) {
        if (j < r) {
            float4 v = poll4(aggA + ((((size_t)(c - r + j) * Bt + b) * 2 + h) * 64 + lane) * 4);
            P.x = fmaf(W1, P.x, v.x); P.y = fmaf(W1, P.y, v.y);
            P.z = fmaf(W1, P.z, v.z); P.w = fmaf(W1, P.w, v.w);
            R.x = fmaf(W1, R.x, v.x); R.y = fmaf(W1, R.y, v.y);
            R.z = fmaf(W1, R.z, v.z); R.w = fmaf(W1, R.w, v.w);
        }
    }
    if (r == 7) {   // S1 producer: fold own A onto remainder fold R
        float4 s1;
        s1.x = fmaf(W1, R.x, A.x); s1.y = fmaf(W1, R.y, A.y);
        s1.z = fmaf(W1, R.z, A.z); s1.w = fmaf(W1, R.w, A.w);
        store4(aggS1 + ((((size_t)(c >> 3) * Bt + b) * 2 + h) * 64 + lane) * 4, s1);
        if (m == 7) {   // S2 producer: fold own S1 onto zero-seed Z
            float4 s2;
            s2.x = fmaf(W2, Z.x, s1.x); s2.y = fmaf(W2, Z.y, s1.y);
            s2.z = fmaf(W2, Z.z, s1.z); s2.w = fmaf(W2, Z.w, s1.w);
            store4(aggS2 + ((((size_t)q * Bt + b) * 2 + h) * 64 + lane) * 4, s2);
        }
    }

    // Final scan seeded with the carry; nontemporal stream out.
    float4 s = P;
    fvec4* qo = (fvec4*)(out4 + base);
    #pragma unroll
    for (int u = 0; u < TSv; ++u) {
        s.x = fmaf(w, s.x, omw * x[u].x);
        s.y = fmaf(w, s.y, omw * x[u].y);
        s.z = fmaf(w, s.z, omw * x[u].z);
        s.w = fmaf(w, s.w, omw * x[u].w);
        fvec4 sn = {s.x, s.y, s.z, s.w};
        __builtin_nontemporal_store(sn, qo + (size_t)u * HD4);
    }
}

}  // namespace

extern "C" void kernel_launch(void* const* d_in, const int* in_sizes, int n_in,
                              void* d_out, int out_size, void* d_ws, size_t ws_size,
                              hipStream_t stream) {
    const float4* values4 = (const float4*)d_in[0];  // [16, 4096, 8, 64] f32
    const float*  sw      = (const float*)d_in[1];   // [8, 1]
    const float4* v04     = (const float4*)d_in[2];  // [1, 1, 8, 64]
    float4* out4 = (float4*)d_out;

    float* aggA   = (float*)d_ws;                     // 16 MiB
    float* aggS1  = aggA  + A_F4  * 4;                // 2 MiB
    float* aggS2  = aggS1 + S1_F4 * 4;                // 256 KiB
    int*   ticket = (int*)(aggS2 + S2_F4 * 4);

    (void)hipMemsetAsync(aggA, 0xFF,
                         (A_F4 + S1_F4 + S2_F4) * 4 * sizeof(float), stream);
    (void)hipMemsetAsync(ticket, 0, sizeof(int), stream);

    ema_wave<<<dim3(NBLK), dim3(512), 0, stream>>>(values4, sw, v04, out4,
                                                   aggA, aggS1, aggS2, ticket);
}

// Round 14
// 61.927 us; speedup vs baseline: 10.1537x; 10.1537x over previous
//
#include <hip/hip_runtime.h>

// Exponential smoothing: s[-1]=v0; s[j] = w*s[j-1] + (1-w)*x[j]; out[j]=s[j]
// w = sigmoid(smoothing_weight[h]).
// Single-pass chained scan; values read ONCE, out written ONCE.
// Round-14 vs round-12 (62.4us best; VGPR=60 < 64 pinned regs -> spill):
//   - 1024-thread blocks, 8 groups x 128 float4-ch, TS=8 -> 32 pinned data
//     regs/thread (round-10's proven spill-free shape) + walk scratch ~ 50
//     total, safely under the 64-reg / 8-waves-per-SIMD boundary
//   - grid still 1024 blocks (CL=64, NC=64); walk still <=7 sg + <=7 chunk
//     polls (serial poll-and-fold, done by threads 0..511)
// Round-13 lesson: polls must stay rare vs payload (this: <=14 polls per
// 128KB output block). Inter-block comm: relaxed agent atomics + 0xFFFFFFFF
// sentinel only (no fences). Fixed-order walk => bit-deterministic. Ticket
// keeps dependency-order = dispatch-order => progress under any residency.

namespace {

constexpr int Bt   = 16;          // batch
constexpr int Tt   = 4096;        // time
constexpr int HD4  = 128;         // float4 channels per (b,t)
constexpr int CL   = 64;          // chunk length
constexpr int NGRP = 8;           // time-groups per chunk
constexpr int TS   = CL / NGRP;   // 8 steps per group
constexpr int NC   = Tt / CL;     // 64 chunks per batch
constexpr int NBLK = NC * Bt;     // 1024
constexpr int NTHR = NGRP * HD4;  // 1024 threads
constexpr unsigned SENT = 0xFFFFFFFFu;

typedef float fvec4 __attribute__((ext_vector_type(4)));

__device__ __forceinline__ float sigmoidf_(float x) {
    return 1.0f / (1.0f + expf(-x));
}

__device__ __forceinline__ unsigned ld_relaxed(const unsigned* p) {
    return __hip_atomic_load(p, __ATOMIC_RELAXED, __HIP_MEMORY_SCOPE_AGENT);
}

__device__ __forceinline__ float poll1(const unsigned* p) {
    unsigned u = ld_relaxed(p);
    while (u == SENT) {
        __builtin_amdgcn_s_sleep(2);
        u = ld_relaxed(p);
    }
    return __uint_as_float(u);
}

__device__ __forceinline__ void store1(float* p, float v) {
    __hip_atomic_store(p, v, __ATOMIC_RELAXED, __HIP_MEMORY_SCOPE_AGENT);
}

__device__ __forceinline__ void store4(float* p, const float4& v) {
    store1(p + 0, v.x); store1(p + 1, v.y);
    store1(p + 2, v.z); store1(p + 3, v.w);
}

__global__ __launch_bounds__(NTHR, 8) void ema_onepass(
    const float4* __restrict__ values4, const float* __restrict__ sw,
    const float* __restrict__ v0f, float4* __restrict__ out4,
    float* __restrict__ aggf, float* __restrict__ sgf,
    int* __restrict__ ticket) {

    __shared__ float4 s_A[NGRP][HD4];    // 16 KiB per-group partial aggs
    __shared__ float4 s_Ab[HD4];         // 2 KiB block aggregate
    __shared__ float4 s_carryv[HD4];     // 2 KiB carry
    __shared__ int s_vid;

    const int tid = threadIdx.x;
    if (tid == 0) s_vid = atomicAdd(ticket, 1);
    __syncthreads();
    const int vid = s_vid;
    const int b = vid & (Bt - 1);
    const int c = vid >> 4;              // chunk; deps have lower vid
    const int ch = tid & (HD4 - 1);
    const int g  = tid >> 7;             // time-group 0..7, wave-uniform

    const float w   = sigmoidf_(sw[ch >> 4]);
    const float omw = 1.0f - w;
    float W8 = w * w;  W8 = W8 * W8;  W8 = W8 * W8;       // w^8

    // Load my 8 time-steps into registers; fold zero-seed partial aggregate.
    const size_t chunkbase = ((size_t)b * Tt + (size_t)c * CL) * HD4 + ch;
    const float4* p = values4 + chunkbase + (size_t)g * TS * HD4;
    float4 x[TS];
    float4 A = make_float4(0.f, 0.f, 0.f, 0.f);
    #pragma unroll
    for (int u = 0; u < TS; ++u) {
        x[u] = p[(size_t)u * HD4];
        A.x = fmaf(w, A.x, omw * x[u].x);
        A.y = fmaf(w, A.y, omw * x[u].y);
        A.z = fmaf(w, A.z, omw * x[u].z);
        A.w = fmaf(w, A.w, omw * x[u].w);
    }
    // Pin the chunk in VGPRs (anti-rematerialization, rounds 5/6 lesson).
    #pragma unroll
    for (int u = 0; u < TS; ++u)
        asm volatile("" : "+v"(x[u].x), "+v"(x[u].y), "+v"(x[u].z), "+v"(x[u].w));

    s_A[g][ch] = A;
    __syncthreads();   // barrier 1

    // Last group folds the block aggregate (8 partials) and publishes.
    if (g == NGRP - 1) {
        float4 t = s_A[0][ch];
        #pragma unroll
        for (int j = 1; j < NGRP; ++j) {
            float4 Aj = (j == NGRP - 1) ? A : s_A[j][ch];
            t.x = fmaf(W8, t.x, Aj.x);
            t.y = fmaf(W8, t.y, Aj.y);
            t.z = fmaf(W8, t.z, Aj.z);
            t.w = fmaf(W8, t.w, Aj.w);
        }
        s_Ab[ch] = t;
        store4(aggf + (((size_t)c * Bt + b) * HD4 + ch) * 4, t);
    }
    __syncthreads();   // barrier 2

    // ---- Carry walk: threads 0..511, one float channel each ----
    if (tid < 512) {
        const float ws = sigmoidf_(sw[tid >> 6]);
        float Wcs = ws * ws;
        #pragma unroll
        for (int i = 0; i < 5; ++i) Wcs = Wcs * Wcs;           // w^64
        float WSGs = Wcs;
        #pragma unroll
        for (int i = 0; i < 3; ++i) WSGs = WSGs * WSGs;        // w^512

        const unsigned* au = (const unsigned*)aggf;
        const unsigned* su = (const unsigned*)sgf;
        const int mf  = c >> 3;          // complete supergroups (SG=8)
        const int k0  = mf << 3;
        const int rem = c - k0;          // 0..7

        // Phase 1: remainder scan R (seed 0), serial poll-and-fold.
        float R = 0.0f;
        #pragma unroll
        for (int j = 0; j < 7; ++j) {
            if (k0 + j < c) {
                float av = poll1(au + ((size_t)(k0 + j) * Bt + b) * (HD4 * 4) + tid);
                R = fmaf(Wcs, R, av);
            }
        }

        // Phase 2: supergroup producer publishes immediately (local deps).
        if ((c & 7) == 7) {
            float ab = ((const float*)s_Ab)[tid];
            store1(sgf + ((size_t)mf * Bt + b) * (HD4 * 4) + tid,
                   fmaf(Wcs, R, ab));
            asm volatile("" ::: "memory");
        }

        // Phase 3: supergroup prefix P (seed v0), serial poll-and-fold.
        float P = v0f[tid];
        #pragma unroll
        for (int j = 0; j < 7; ++j) {
            if (j < mf) {
                float svv = poll1(su + ((size_t)j * Bt + b) * (HD4 * 4) + tid);
                P = fmaf(WSGs, P, svv);
            }
        }

        // carry = Wc^rem * P + R   (rem in 0..7)
        float Wr = 1.0f, pw = Wcs;
        if (rem & 1) Wr *= pw;  pw *= pw;
        if (rem & 2) Wr *= pw;  pw *= pw;
        if (rem & 4) Wr *= pw;
        ((float*)s_carryv)[tid] = fmaf(Wr, P, R);
    }
    __syncthreads();   // barrier 3

    // Group seed: fold partial aggs of groups < g onto the carry.
    float4 s = s_carryv[ch];
    #pragma unroll
    for (int j = 0; j < NGRP - 1; ++j) {
        if (j < g) {
            float4 Aj = s_A[j][ch];
            s.x = fmaf(W8, s.x, Aj.x);
            s.y = fmaf(W8, s.y, Aj.y);
            s.z = fmaf(W8, s.z, Aj.z);
            s.w = fmaf(W8, s.w, Aj.w);
        }
    }

    // Final scan from registers; nontemporal stream out.
    fvec4* q = (fvec4*)(out4 + chunkbase + (size_t)g * TS * HD4);
    #pragma unroll
    for (int u = 0; u < TS; ++u) {
        s.x = fmaf(w, s.x, omw * x[u].x);
        s.y = fmaf(w, s.y, omw * x[u].y);
        s.z = fmaf(w, s.z, omw * x[u].z);
        s.w = fmaf(w, s.w, omw * x[u].w);
        fvec4 sn = {s.x, s.y, s.z, s.w};
        __builtin_nontemporal_store(sn, q + (size_t)u * HD4);
    }
}

}  // namespace

extern "C" void kernel_launch(void* const* d_in, const int* in_sizes, int n_in,
                              void* d_out, int out_size, void* d_ws, size_t ws_size,
                              hipStream_t stream) {
    const float4* values4 = (const float4*)d_in[0];  // [16, 4096, 8, 64] f32
    const float*  sw      = (const float*)d_in[1];   // [8, 1]
    const float*  v0f     = (const float*)d_in[2];   // [1, 1, 8, 64] = 512 f32
    float4* out4 = (float4*)d_out;

    const size_t aggFloats = (size_t)NC * Bt * HD4 * 4;        // 2 MiB
    const size_t sgFloats  = (size_t)(NC / 8) * Bt * HD4 * 4;  // 256 KiB
    float* aggf   = (float*)d_ws;
    float* sgf    = aggf + aggFloats;
    int*   ticket = (int*)(sgf + sgFloats);

    (void)hipMemsetAsync(aggf, 0xFF, (aggFloats + sgFloats) * sizeof(float), stream);
    (void)hipMemsetAsync(ticket, 0, sizeof(int), stream);

    ema_onepass<<<dim3(NBLK), dim3(NTHR), 0, stream>>>(values4, sw, v0f, out4,
                                                       aggf, sgf, ticket);
}